// Round 1
// baseline (3133.517 us; speedup 1.0000x reference)
//
#include <hip/hip_runtime.h>
#include <cmath>

#define B_   128
#define T_   64
#define IN_  2048
#define OUT_ 2048
#define IDXSTRIDE 512   // max active inputs per (b,t); Binomial(2048,0.1) ~ 205 +- 14, 512 is +22 sigma
#define OSEG 512        // outputs per spike-block

// double-precision constants == Python float64 literals
#define BETA_D   0.9
#define ACTDEC_D 0.999
#define ETA_TH_D 0.001
#define TARGET_D 0.05
#define MINW_D   (-5.0)
#define MAXW_D   (5.0)
#define MINTH_D  0.5
#define MAXTH_D  2.0

// ---- one-time: W (OUT,IN) fp32 -> WT (IN,OUT) fp64 ----
__global__ __launch_bounds__(256) void k_transpose(const float* __restrict__ W,
                                                   double* __restrict__ WT) {
    __shared__ float tile[32][33];
    int bx = blockIdx.x * 32;   // i (W col)
    int by = blockIdx.y * 32;   // o (W row)
    int tx = threadIdx.x & 31;
    int ty = threadIdx.x >> 5;  // 0..7
#pragma unroll
    for (int r = ty; r < 32; r += 8)
        tile[r][tx] = W[(size_t)(by + r) * IN_ + bx + tx];
    __syncthreads();
#pragma unroll
    for (int r = ty; r < 32; r += 8)
        WT[(size_t)(bx + r) * OUT_ + by + tx] = (double)tile[tx][r];
}

// ---- one-time: init state ----
__global__ __launch_bounds__(256) void k_init(const float* __restrict__ thr_in,
        double* __restrict__ v, double* __restrict__ th, double* __restrict__ pre_tr,
        double* __restrict__ post_tr, double* __restrict__ post_act,
        float* __restrict__ pre_sum, float* __restrict__ post_sum) {
    int gid = blockIdx.x * 256 + threadIdx.x;
    if (gid < B_ * OUT_) v[gid] = 0.0;
    if (gid < OUT_) {
        th[gid]       = (double)thr_in[gid];
        pre_tr[gid]   = 0.0;
        post_tr[gid]  = 0.0;
        post_act[gid] = TARGET_D;
        pre_sum[gid]  = 0.0f;
        post_sum[gid] = 0.0f;
    }
}

// ---- one-time: ballot-compact x (0/1) into ascending index lists per (b,t) ----
__global__ __launch_bounds__(256) void k_build_idx(const float* __restrict__ x,
        unsigned short* __restrict__ idx, int* __restrict__ cnt) {
    int row  = blockIdx.x * 4 + (threadIdx.x >> 6);   // b*T + t
    int lane = threadIdx.x & 63;
    const float* xr = x + (size_t)row * IN_;
    unsigned short* ip = idx + (size_t)row * IDXSTRIDE;
    int c = 0;
    for (int ch = 0; ch < IN_ / 64; ++ch) {
        float vv = xr[ch * 64 + lane];
        unsigned long long m = __ballot(vv != 0.0f);
        if (vv != 0.0f) {
            int pos = c + __popcll(m & ((1ull << lane) - 1ull));
            if (pos < IDXSTRIDE) ip[pos] = (unsigned short)(ch * 64 + lane);
        }
        c += __popcll(m);
    }
    if (lane == 0) cnt[row] = (c < IDXSTRIDE) ? c : IDXSTRIDE;
}

// ---- per step: sparse fp64 accumulate + LIF threshold + spike counts ----
__global__ __launch_bounds__(256) void k_spike(const unsigned short* __restrict__ idx,
        const int* __restrict__ cnt, const double* __restrict__ WT,
        double* __restrict__ v, const double* __restrict__ th,
        float* __restrict__ out, float* __restrict__ post_sum,
        float* __restrict__ pre_sum, int t) {
    int b    = blockIdx.x;
    int oseg = blockIdx.y;
    int row  = b * T_ + t;
    int n    = cnt[row];
    const unsigned short* ip = idx + (size_t)row * IDXSTRIDE;
    int o = oseg * OSEG + threadIdx.x * 2;

    double a0 = 0.0, a1 = 0.0;
    int j = 0;
    for (; j + 8 <= n; j += 8) {
        uint4 c4 = *(const uint4*)(ip + j);   // 8 indices, wave-uniform load
        int ii[8];
        ii[0] = c4.x & 0xffff; ii[1] = (int)(c4.x >> 16);
        ii[2] = c4.y & 0xffff; ii[3] = (int)(c4.y >> 16);
        ii[4] = c4.z & 0xffff; ii[5] = (int)(c4.z >> 16);
        ii[6] = c4.w & 0xffff; ii[7] = (int)(c4.w >> 16);
#pragma unroll
        for (int u = 0; u < 8; ++u) {
            double2 w = *(const double2*)&WT[((size_t)ii[u] << 11) + o];
            a0 += w.x; a1 += w.y;
        }
    }
    for (; j < n; ++j) {
        int i = ip[j];
        double2 w = *(const double2*)&WT[((size_t)i << 11) + o];
        a0 += w.x; a1 += w.y;
    }

    size_t vo = (size_t)b * OUT_ + o;
    double v0 = BETA_D * v[vo]     + a0;
    double v1 = BETA_D * v[vo + 1] + a1;
    double t0 = th[o], t1 = th[o + 1];
    float s0 = (v0 >= t0) ? 1.0f : 0.0f;
    float s1 = (v1 >= t1) ? 1.0f : 0.0f;
    *(float2*)&out[(size_t)row * OUT_ + o] = make_float2(s0, s1);
    v[vo]     = (s0 != 0.0f) ? 0.0 : v0;
    v[vo + 1] = (s1 != 0.0f) ? 0.0 : v1;
    // spike counts: integer-valued float atomics -> exact & order-independent
    if (s0 != 0.0f) atomicAdd(&post_sum[o], 1.0f);
    if (s1 != 0.0f) atomicAdd(&post_sum[o + 1], 1.0f);
    if (oseg == 0) {  // input counts from the (distinct) index list
        for (int k = threadIdx.x; k < n; k += 256) atomicAdd(&pre_sum[ip[k]], 1.0f);
    }
}

// ---- per step: traces / threshold / meta -> row & col coefficients ----
__global__ __launch_bounds__(256) void k_vec(const float* __restrict__ pre_sum,
        const float* __restrict__ post_sum, double* __restrict__ pre_tr,
        double* __restrict__ post_tr, double* __restrict__ post_act,
        double* __restrict__ th, double* __restrict__ pre_rate,
        double* __restrict__ co_a, double* __restrict__ co_b,
        const float* __restrict__ Ap, const float* __restrict__ Am,
        double trace_decay) {
    int o = blockIdx.x * 256 + threadIdx.x;   // serves both i-space and o-space (2048)
    double prate = (double)pre_sum[o] * (1.0 / 128.0);          // exact
    double ptr_  = trace_decay * pre_tr[o] + prate;
    pre_tr[o]   = ptr_;
    pre_rate[o] = prate;
    double porate = (double)post_sum[o] * (1.0 / 128.0);
    double potr   = trace_decay * post_tr[o] + porate;
    post_tr[o] = potr;
    double pact = ACTDEC_D * post_act[o] + (1.0 - ACTDEC_D) * porate;
    post_act[o] = pact;
    double r = pact / TARGET_D;
    r = r < 0.5 ? 0.5 : (r > 2.0 ? 2.0 : r);
    double meta = 1.0 / r;
    co_a[o] = fabs((double)Ap[0]) * porate * meta;   // LTP row coeff
    co_b[o] = fabs((double)Am[0]) * potr   * meta;   // LTD row coeff
    double thv = th[o] * (1.0 + ETA_TH_D * (porate - TARGET_D));
    th[o] = thv < MINTH_D ? MINTH_D : (thv > MAXTH_D ? MAXTH_D : thv);
}

// ---- per step: elementwise soft-bounded STDP update of WT (fp64) ----
__global__ __launch_bounds__(256) void k_wupd(double* __restrict__ WT,
        const double* __restrict__ pre_tr, const double* __restrict__ pre_rate,
        const double* __restrict__ co_a, const double* __restrict__ co_b,
        float* __restrict__ pre_sum, float* __restrict__ post_sum) {
    int gid = blockIdx.x * 256 + threadIdx.x;   // over IN*OUT/2
    int i  = gid >> 10;              // / (OUT/2)
    int o  = (gid & 1023) * 2;
    double p = pre_tr[i], q = pre_rate[i];
    size_t off = ((size_t)i << 11) + o;
    double2 w2 = *(const double2*)&WT[off];
    double dw0 = co_a[o]     * p - co_b[o]     * q;
    double dw1 = co_a[o + 1] * p - co_b[o + 1] * q;
    // soft bounds, matching np eval order: (dw*(bound-term)) / 10.0
    double dwb0 = dw0 > 0.0 ? (dw0 * (MAXW_D - w2.x)) / 10.0 : (dw0 * (w2.x - MINW_D)) / 10.0;
    double dwb1 = dw1 > 0.0 ? (dw1 * (MAXW_D - w2.y)) / 10.0 : (dw1 * (w2.y - MINW_D)) / 10.0;
    double nw0 = w2.x + dwb0; nw0 = nw0 < MINW_D ? MINW_D : (nw0 > MAXW_D ? MAXW_D : nw0);
    double nw1 = w2.y + dwb1; nw1 = nw1 < MINW_D ? MINW_D : (nw1 > MAXW_D ? MAXW_D : nw1);
    *(double2*)&WT[off] = make_double2(nw0, nw1);
    if (blockIdx.x == 0) {   // zero count buffers for next step
#pragma unroll
        for (int k2 = 0; k2 < 8; ++k2) {
            pre_sum[threadIdx.x + k2 * 256]  = 0.0f;
            post_sum[threadIdx.x + k2 * 256] = 0.0f;
        }
    }
}

extern "C" void kernel_launch(void* const* d_in, const int* in_sizes, int n_in,
                              void* d_out, int out_size, void* d_ws, size_t ws_size,
                              hipStream_t stream) {
    const float* x   = (const float*)d_in[0];
    const float* W   = (const float*)d_in[1];
    const float* thr = (const float*)d_in[2];
    const float* Ap  = (const float*)d_in[3];
    const float* Am  = (const float*)d_in[4];
    float* out = (float*)d_out;
    char* ws = (char*)d_ws;

    // workspace layout (total ~44.2 MB)
    double* WT       = (double*)(ws);                         // 33,554,432 B
    double* v        = (double*)(ws + 33554432);              //  2,097,152
    double* th       = (double*)(ws + 35651584);              //     16,384
    double* pre_tr   = (double*)(ws + 35667968);
    double* post_tr  = (double*)(ws + 35684352);
    double* post_act = (double*)(ws + 35700736);
    double* pre_rate = (double*)(ws + 35717120);
    double* co_a     = (double*)(ws + 35733504);
    double* co_b     = (double*)(ws + 35749888);
    float*  pre_sum  = (float*)(ws + 35766272);               //      8,192
    float*  post_sum = (float*)(ws + 35774464);               //      8,192
    unsigned short* idx = (unsigned short*)(ws + 35782656);   //  8,388,608
    int*    cnt      = (int*)(ws + 35782656 + 8388608);       //     32,768

    double trace_decay = std::exp(-1.0 / 20.0);   // matches np.exp(-1/20) float64

    k_transpose<<<dim3(IN_ / 32, OUT_ / 32), 256, 0, stream>>>(W, WT);
    k_init<<<(B_ * OUT_ + 255) / 256, 256, 0, stream>>>(thr, v, th, pre_tr, post_tr,
                                                        post_act, pre_sum, post_sum);
    k_build_idx<<<(B_ * T_) / 4, 256, 0, stream>>>(x, idx, cnt);

    for (int t = 0; t < T_; ++t) {
        k_spike<<<dim3(B_, OUT_ / OSEG), 256, 0, stream>>>(idx, cnt, WT, v, th, out,
                                                           post_sum, pre_sum, t);
        if (t + 1 < T_) {   // final-step W/trace updates don't affect the output
            k_vec<<<OUT_ / 256, 256, 0, stream>>>(pre_sum, post_sum, pre_tr, post_tr,
                                                  post_act, th, pre_rate, co_a, co_b,
                                                  Ap, Am, trace_decay);
            k_wupd<<<(IN_ * OUT_ / 2) / 256, 256, 0, stream>>>(WT, pre_tr, pre_rate,
                                                               co_a, co_b, pre_sum, post_sum);
        }
    }
}

// Round 2
// 1037.541 us; speedup vs baseline: 3.0201x; 3.0201x over previous
//
#include <hip/hip_runtime.h>
#include <cmath>

#define B_   128
#define T_   64
#define IN_  2048
#define OUT_ 2048
#define IDXSTRIDE 512   // max active inputs per (b,t); Binomial(2048,0.1) ~ 205 +- 14

// fp64 constants == Python float64 literals
#define BETA_D   0.9
#define ACTDEC_D 0.999
#define ETA_TH_D 0.001
#define TARGET_D 0.05
#define MINW_D   (-5.0)
#define MAXW_D   (5.0)
#define MINTH_D  0.5
#define MAXTH_D  2.0

// LDS layout (bytes). Wl: 2048 rows x 8 cols fp64, col-pair-swizzled:
//   col-pair p of row i lives at  i*64 + ((p ^ (i&3))<<4)  (+8 for odd col)
#define WL_OFF   0
#define VL_OFF   131072   // v[128][8] fp64
#define TH_OFF   139264   // th[8]
#define PTR_OFF  139328   // post_tr[8]
#define PACT_OFF 139392   // post_act[8]
#define COA_OFF  139456   // co_a[8]
#define COB_OFF  139520   // co_b[8]
#define PART_OFF 139584   // partial spike counts [8 waves][8 cols] f32
#define SMEM_BYTES 139840

// ---- precompute: pre_rate[t][i] = mean_b x[b,t,i]  (exact: integer counts) ----
__global__ __launch_bounds__(256) void k_rate(const float* __restrict__ x,
                                              double* __restrict__ pre_rate) {
    int t = blockIdx.x;
    int i = blockIdx.y * 256 + threadIdx.x;
    const float* xp = x + (size_t)t * IN_ + i;
    float s = 0.f;
    for (int b = 0; b < B_; ++b) s += xp[(size_t)b * T_ * IN_];
    pre_rate[(size_t)t * IN_ + i] = (double)s * (1.0 / 128.0);
}

// ---- precompute: pre_tr[t][i] = decay*pre_tr[t-1][i] + pre_rate[t][i] ----
__global__ __launch_bounds__(256) void k_scan(const double* __restrict__ pre_rate,
                                              double* __restrict__ pre_tr, double decay) {
    int i = blockIdx.x * 256 + threadIdx.x;
    double tr = 0.0;
    for (int t = 0; t < T_; ++t) {
        tr = decay * tr + pre_rate[(size_t)t * IN_ + i];
        pre_tr[(size_t)t * IN_ + i] = tr;
    }
}

// ---- ballot-compact x (0/1) into ascending index lists per (b,t) ----
__global__ __launch_bounds__(256) void k_build_idx(const float* __restrict__ x,
        unsigned short* __restrict__ idx, int* __restrict__ cnt) {
    int row  = blockIdx.x * 4 + (threadIdx.x >> 6);   // b*T + t
    int lane = threadIdx.x & 63;
    const float* xr = x + (size_t)row * IN_;
    unsigned short* ip = idx + (size_t)row * IDXSTRIDE;
    int c = 0;
    for (int ch = 0; ch < IN_ / 64; ++ch) {
        float vv = xr[ch * 64 + lane];
        unsigned long long m = __ballot(vv != 0.0f);
        if (vv != 0.0f) {
            int pos = c + __popcll(m & ((1ull << lane) - 1ull));
            if (pos < IDXSTRIDE) ip[pos] = (unsigned short)(ch * 64 + lane);
        }
        c += __popcll(m);
    }
    if (lane == 0) cnt[row] = (c < IDXSTRIDE) ? c : IDXSTRIDE;
}

// gather one swizzled col-pair of row ii and accumulate
#define GAT(ii) do { \
    const double2 w_ = *(const double2*)(smem + ((unsigned)(ii) << 6) + \
                                         ((unsigned)(c2 ^ ((ii) & 3)) << 4)); \
    a0 += w_.x; a1 += w_.y; } while (0)

// ---- persistent kernel: 256 blocks x 512 threads; block s owns cols [s*8, s*8+8) ----
__global__ __launch_bounds__(512, 1) void k_main(
        const float* __restrict__ W, const float* __restrict__ thr,
        const float* __restrict__ Ap, const float* __restrict__ Am,
        const unsigned short* __restrict__ idx, const int* __restrict__ cnt,
        const double* __restrict__ pre_rate, const double* __restrict__ pre_tr,
        float* __restrict__ out, double decay) {
    extern __shared__ char smem[];
    double* vL    = (double*)(smem + VL_OFF);
    double* thL   = (double*)(smem + TH_OFF);
    double* ptrL  = (double*)(smem + PTR_OFF);
    double* pactL = (double*)(smem + PACT_OFF);
    double* coaL  = (double*)(smem + COA_OFF);
    double* cobL  = (double*)(smem + COB_OFF);
    float*  part  = (float*)(smem + PART_OFF);

    const int tid = threadIdx.x;
    const int s   = blockIdx.x;

    // ---- prologue: load W shard (rows s*8..s*8+8 of W = our 8 cols), fp64, swizzled ----
#pragma unroll
    for (int o = 0; o < 8; ++o) {
        const float* wr = W + (size_t)(s * 8 + o) * IN_;
        for (int i = tid; i < IN_; i += 512) {
            *(double*)(smem + ((unsigned)i << 6) +
                       ((unsigned)((o >> 1) ^ (i & 3)) << 4) + ((o & 1) << 3)) = (double)wr[i];
        }
    }
    for (int e = tid; e < B_ * 8; e += 512) vL[e] = 0.0;
    if (tid < 8) {
        thL[tid]   = (double)thr[s * 8 + tid];
        ptrL[tid]  = 0.0;
        pactL[tid] = TARGET_D;
    }
    __syncthreads();

    const int b  = tid >> 2;   // 0..127
    const int c2 = tid & 3;    // col-pair: owns cols {2c2, 2c2+1}

    for (int t = 0; t < T_; ++t) {
        // ---- P1: sparse fp64 gather-accumulate + LIF + spike counts ----
        int row = b * T_ + t;
        int n = cnt[row];
        const unsigned short* ip = idx + (size_t)row * IDXSTRIDE;
        double a0 = 0.0, a1 = 0.0;
        int n8 = n & ~7;
        int j = 0;
        if (n8 > 0) {
            uint4 q = *(const uint4*)(ip);
            for (;;) {
                uint4 qc = q;
                int jn = j + 8;
                if (jn < n8) q = *(const uint4*)(ip + jn);   // prefetch next group
                int i0 = qc.x & 0xffff, i1 = qc.x >> 16;
                int i2 = qc.y & 0xffff, i3 = qc.y >> 16;
                int i4 = qc.z & 0xffff, i5 = qc.z >> 16;
                int i6 = qc.w & 0xffff, i7 = qc.w >> 16;
                GAT(i0); GAT(i1); GAT(i2); GAT(i3);
                GAT(i4); GAT(i5); GAT(i6); GAT(i7);
                j = jn;
                if (j >= n8) break;
            }
        }
        for (; j < n; ++j) { int ii = ip[j]; GAT(ii); }

        double2 vv = *(double2*)&vL[b * 8 + c2 * 2];
        double v0 = BETA_D * vv.x + a0;
        double v1 = BETA_D * vv.y + a1;
        double t0 = thL[c2 * 2], t1 = thL[c2 * 2 + 1];
        float s0 = (v0 >= t0) ? 1.0f : 0.0f;
        float s1 = (v1 >= t1) ? 1.0f : 0.0f;
        *(float2*)(out + (size_t)row * OUT_ + s * 8 + c2 * 2) = make_float2(s0, s1);
        vv.x = (s0 != 0.0f) ? 0.0 : v0;
        vv.y = (s1 != 0.0f) ? 0.0 : v1;
        *(double2*)&vL[b * 8 + c2 * 2] = vv;

        // reduce spike counts over the 16 b-lanes of this wave (lane bits 2..5)
        float r0 = s0, r1 = s1;
        r0 += __shfl_xor(r0, 4);  r1 += __shfl_xor(r1, 4);
        r0 += __shfl_xor(r0, 8);  r1 += __shfl_xor(r1, 8);
        r0 += __shfl_xor(r0, 16); r1 += __shfl_xor(r1, 16);
        r0 += __shfl_xor(r0, 32); r1 += __shfl_xor(r1, 32);
        if ((tid & 63) < 4)
            *(float2*)&part[(tid >> 6) * 8 + c2 * 2] = make_float2(r0, r1);
        __syncthreads();

        // ---- P2: per-column scalar chain (8 lanes) ----
        if (tid < 8) {
            int c = tid;
            float cf = 0.f;
#pragma unroll
            for (int w8 = 0; w8 < 8; ++w8) cf += part[w8 * 8 + c];
            double prate = (double)cf * (1.0 / 128.0);
            double ptr2 = decay * ptrL[c] + prate;            ptrL[c] = ptr2;
            double pact = ACTDEC_D * pactL[c] + (1.0 - ACTDEC_D) * prate;  pactL[c] = pact;
            double r = pact / TARGET_D;
            r = r < 0.5 ? 0.5 : (r > 2.0 ? 2.0 : r);
            double meta = 1.0 / r;
            double apv = fabs((double)Ap[0]);
            double amv = fabs((double)Am[0]);
            coaL[c] = apv * prate * meta;
            cobL[c] = amv * ptr2 * meta;
            double thv = thL[c] * (1.0 + ETA_TH_D * (prate - TARGET_D));
            thL[c] = thv < MINTH_D ? MINTH_D : (thv > MAXTH_D ? MAXTH_D : thv);
        }
        __syncthreads();

        // ---- P3: in-LDS soft-bounded STDP update of W shard ----
        if (t + 1 < T_) {
            double ca0 = coaL[c2 * 2], ca1 = coaL[c2 * 2 + 1];
            double cb0 = cobL[c2 * 2], cb1 = cobL[c2 * 2 + 1];
            const double* prt = pre_tr   + (size_t)t * IN_;
            const double* prr = pre_rate + (size_t)t * IN_;
#pragma unroll 4
            for (int k = 0; k < 16; ++k) {
                int i = k * 128 + b;
                double p = prt[i], q = prr[i];
                double2* wp = (double2*)(smem + ((unsigned)i << 6) +
                                         ((unsigned)(c2 ^ (i & 3)) << 4));
                double2 w2 = *wp;
                double dw0 = ca0 * p - cb0 * q;
                double dw1 = ca1 * p - cb1 * q;
                double dwb0 = dw0 > 0.0 ? (dw0 * (MAXW_D - w2.x)) / 10.0
                                        : (dw0 * (w2.x - MINW_D)) / 10.0;
                double dwb1 = dw1 > 0.0 ? (dw1 * (MAXW_D - w2.y)) / 10.0
                                        : (dw1 * (w2.y - MINW_D)) / 10.0;
                double nw0 = w2.x + dwb0;
                nw0 = nw0 < MINW_D ? MINW_D : (nw0 > MAXW_D ? MAXW_D : nw0);
                double nw1 = w2.y + dwb1;
                nw1 = nw1 < MINW_D ? MINW_D : (nw1 > MAXW_D ? MAXW_D : nw1);
                *wp = make_double2(nw0, nw1);
            }
        }
        __syncthreads();
    }
}

extern "C" void kernel_launch(void* const* d_in, const int* in_sizes, int n_in,
                              void* d_out, int out_size, void* d_ws, size_t ws_size,
                              hipStream_t stream) {
    const float* x   = (const float*)d_in[0];
    const float* W   = (const float*)d_in[1];
    const float* thr = (const float*)d_in[2];
    const float* Ap  = (const float*)d_in[3];
    const float* Am  = (const float*)d_in[4];
    float* out = (float*)d_out;
    char* ws = (char*)d_ws;

    // workspace: pre_rate 1MB | pre_tr 1MB | idx 8.4MB | cnt 32KB  (~10.5 MB)
    double* pre_rate = (double*)(ws);
    double* pre_tr   = (double*)(ws + 1048576);
    unsigned short* idx = (unsigned short*)(ws + 2097152);
    int* cnt = (int*)(ws + 2097152 + 8388608);

    double decay = std::exp(-1.0 / 20.0);

    (void)hipFuncSetAttribute((const void*)k_main,
                              hipFuncAttributeMaxDynamicSharedMemorySize, SMEM_BYTES);

    k_rate<<<dim3(T_, IN_ / 256), 256, 0, stream>>>(x, pre_rate);
    k_scan<<<IN_ / 256, 256, 0, stream>>>(pre_rate, pre_tr, decay);
    k_build_idx<<<(B_ * T_) / 4, 256, 0, stream>>>(x, idx, cnt);
    k_main<<<256, 512, SMEM_BYTES, stream>>>(W, thr, Ap, Am, idx, cnt,
                                             pre_rate, pre_tr, out, decay);
}

// Round 3
// 879.271 us; speedup vs baseline: 3.5638x; 1.1800x over previous
//
#include <hip/hip_runtime.h>
#include <cmath>

#define B_   128
#define T_   64
#define IN_  2048
#define OUT_ 2048
#define IDXSTRIDE 512   // max active inputs per (b,t); Binomial(2048,0.1) ~ 205 +- 14

// fp64 constants == Python float64 literals
#define BETA_D   0.9
#define ACTDEC_D 0.999
#define ETA_TH_D 0.001
#define TARGET_D 0.05
#define MINW_D   (-5.0)
#define MAXW_D   (5.0)
#define MINTH_D  0.5
#define MAXTH_D  2.0

// LDS layout (bytes). Wl: 2048 rows x 8 cols fp64.
// hash swizzle: s_i = (i ^ (i>>2)) & 3;  col-pair p of row i at
//   (i<<6) | ((p ^ s_i)<<4)  (+8 for odd col)  ==  swadr(i) ^ (p<<4)
// swadr(i) = (i<<6) | (s_i<<4)  -- precomputed into the index lists.
#define SWADR(i) (((unsigned)(i) << 6) | ((((unsigned)(i) ^ ((unsigned)(i) >> 2)) & 3u) << 4))
#define VL_OFF   131072   // v[128][8] fp64
#define TH_OFF   139264   // th[8]
#define PTR_OFF  139328   // post_tr[8]
#define PACT_OFF 139392   // post_act[8]
#define COA_OFF  139456   // co_a[8]
#define COB_OFF  139520   // co_b[8]
#define PART_OFF 139584   // partial spike counts [8 waves][8 cols] f32
#define SMEM_BYTES 139840

// ---- precompute: pre_rate[t][i] = mean_b x[b,t,i]  (exact: integer counts) ----
__global__ __launch_bounds__(256) void k_rate(const float* __restrict__ x,
                                              double* __restrict__ pre_rate) {
    int t = blockIdx.x;
    int i = blockIdx.y * 256 + threadIdx.x;
    const float* xp = x + (size_t)t * IN_ + i;
    float s = 0.f;
    for (int b = 0; b < B_; ++b) s += xp[(size_t)b * T_ * IN_];
    pre_rate[(size_t)t * IN_ + i] = (double)s * (1.0 / 128.0);
}

// ---- precompute: pre_tr[t][i] = decay*pre_tr[t-1][i] + pre_rate[t][i] ----
__global__ __launch_bounds__(256) void k_scan(const double* __restrict__ pre_rate,
                                              double* __restrict__ pre_tr, double decay) {
    int i = blockIdx.x * 256 + threadIdx.x;
    double tr = 0.0;
    for (int t = 0; t < T_; ++t) {
        tr = decay * tr + pre_rate[(size_t)t * IN_ + i];
        pre_tr[(size_t)t * IN_ + i] = tr;
    }
}

// ---- ballot-compact x (0/1) into lists of PRE-SWIZZLED byte offsets per (b,t) ----
__global__ __launch_bounds__(256) void k_build_idx(const float* __restrict__ x,
        unsigned* __restrict__ idx, int* __restrict__ cnt) {
    int row  = blockIdx.x * 4 + (threadIdx.x >> 6);   // b*T + t
    int lane = threadIdx.x & 63;
    const float* xr = x + (size_t)row * IN_;
    unsigned* ip = idx + (size_t)row * IDXSTRIDE;
    int c = 0;
    for (int ch = 0; ch < IN_ / 64; ++ch) {
        int i = ch * 64 + lane;
        float vv = xr[i];
        unsigned long long m = __ballot(vv != 0.0f);
        if (vv != 0.0f) {
            int pos = c + __popcll(m & ((1ull << lane) - 1ull));
            if (pos < IDXSTRIDE) ip[pos] = SWADR(i);
        }
        c += __popcll(m);
    }
    if (lane == 0) cnt[row] = (c < IDXSTRIDE) ? c : IDXSTRIDE;
}

// gather one swizzled col-pair given precomputed byte offset r
#define GAT(r, A0, A1) do { \
    const double2 w_ = *(const double2*)(smem + ((r) ^ cx)); \
    A0 += w_.x; A1 += w_.y; } while (0)

// ---- persistent kernel: 256 blocks x 512 threads; block s owns cols [s*8, s*8+8) ----
__global__ __launch_bounds__(512, 1) void k_main(
        const float* __restrict__ W, const float* __restrict__ thr,
        const float* __restrict__ Ap, const float* __restrict__ Am,
        const unsigned* __restrict__ idx, const int* __restrict__ cnt,
        const double* __restrict__ pre_rate, const double* __restrict__ pre_tr,
        float* __restrict__ out, double decay) {
    extern __shared__ char smem[];
    double* vL    = (double*)(smem + VL_OFF);
    double* thL   = (double*)(smem + TH_OFF);
    double* ptrL  = (double*)(smem + PTR_OFF);
    double* pactL = (double*)(smem + PACT_OFF);
    double* coaL  = (double*)(smem + COA_OFF);
    double* cobL  = (double*)(smem + COB_OFF);
    float*  part  = (float*)(smem + PART_OFF);

    const int tid = threadIdx.x;
    const int s   = blockIdx.x;

    // ---- prologue: load W shard (rows s*8..s*8+8 of W = our 8 cols), fp64, swizzled ----
#pragma unroll
    for (int o = 0; o < 8; ++o) {
        const float* wr = W + (size_t)(s * 8 + o) * IN_;
        for (int i = tid; i < IN_; i += 512) {
            *(double*)(smem + ((SWADR(i) ^ ((unsigned)(o >> 1) << 4)) | ((unsigned)(o & 1) << 3)))
                = (double)wr[i];
        }
    }
    for (int e = tid; e < B_ * 8; e += 512) vL[e] = 0.0;
    if (tid < 8) {
        thL[tid]   = (double)thr[s * 8 + tid];
        ptrL[tid]  = 0.0;
        pactL[tid] = TARGET_D;
    }
    const double apv = fabs((double)Ap[0]);
    const double amv = fabs((double)Am[0]);
    __syncthreads();

    const int b  = tid >> 2;           // 0..127
    const int c2 = tid & 3;            // col-pair: owns cols {2c2, 2c2+1}
    const unsigned cx = (unsigned)c2 << 4;

    for (int t = 0; t < T_; ++t) {
        // ---- P1: sparse fp64 gather-accumulate + LIF + spike counts ----
        int row = b * T_ + t;
        int n = cnt[row];
        const unsigned* ip = idx + (size_t)row * IDXSTRIDE;
        double a0 = 0.0, a1 = 0.0, b0 = 0.0, b1 = 0.0;
        int n8 = n & ~7;
        int j = 0;
        if (n8 > 0) {
            uint4 q0 = *(const uint4*)(ip);
            uint4 q1 = *(const uint4*)(ip + 4);
            for (;;) {
                uint4 qa = q0, qb = q1;
                int jn = j + 8;
                if (jn < n8) {                       // prefetch next group
                    q0 = *(const uint4*)(ip + jn);
                    q1 = *(const uint4*)(ip + jn + 4);
                }
                GAT(qa.x, a0, a1); GAT(qa.y, b0, b1);
                GAT(qa.z, a0, a1); GAT(qa.w, b0, b1);
                GAT(qb.x, a0, a1); GAT(qb.y, b0, b1);
                GAT(qb.z, a0, a1); GAT(qb.w, b0, b1);
                j = jn;
                if (j >= n8) break;
            }
        }
        for (; j < n; ++j) { unsigned r = ip[j]; GAT(r, a0, a1); }
        a0 += b0; a1 += b1;

        double2 vv = *(double2*)&vL[b * 8 + c2 * 2];
        double v0 = BETA_D * vv.x + a0;
        double v1 = BETA_D * vv.y + a1;
        double t0 = thL[c2 * 2], t1 = thL[c2 * 2 + 1];
        float s0 = (v0 >= t0) ? 1.0f : 0.0f;
        float s1 = (v1 >= t1) ? 1.0f : 0.0f;
        *(float2*)(out + (size_t)row * OUT_ + s * 8 + c2 * 2) = make_float2(s0, s1);
        vv.x = (s0 != 0.0f) ? 0.0 : v0;
        vv.y = (s1 != 0.0f) ? 0.0 : v1;
        *(double2*)&vL[b * 8 + c2 * 2] = vv;

        // reduce spike counts over the 16 b-lanes of this wave (lane bits 2..5)
        float r0 = s0, r1 = s1;
        r0 += __shfl_xor(r0, 4);  r1 += __shfl_xor(r1, 4);
        r0 += __shfl_xor(r0, 8);  r1 += __shfl_xor(r1, 8);
        r0 += __shfl_xor(r0, 16); r1 += __shfl_xor(r1, 16);
        r0 += __shfl_xor(r0, 32); r1 += __shfl_xor(r1, 32);
        if ((tid & 63) < 4)
            *(float2*)&part[(tid >> 6) * 8 + c2 * 2] = make_float2(r0, r1);
        __syncthreads();

        // ---- P2: per-column scalar chain (8 lanes) ----
        if (tid < 8) {
            int c = tid;
            float cf = 0.f;
#pragma unroll
            for (int w8 = 0; w8 < 8; ++w8) cf += part[w8 * 8 + c];
            double prate = (double)cf * (1.0 / 128.0);
            double ptr2 = decay * ptrL[c] + prate;            ptrL[c] = ptr2;
            double pact = ACTDEC_D * pactL[c] + (1.0 - ACTDEC_D) * prate;  pactL[c] = pact;
            double r = pact / TARGET_D;
            r = r < 0.5 ? 0.5 : (r > 2.0 ? 2.0 : r);
            double meta = 1.0 / r;
            coaL[c] = apv * prate * meta;
            cobL[c] = amv * ptr2 * meta;
            double thv = thL[c] * (1.0 + ETA_TH_D * (prate - TARGET_D));
            thL[c] = thv < MINTH_D ? MINTH_D : (thv > MAXTH_D ? MAXTH_D : thv);
        }
        __syncthreads();

        // ---- P3: in-LDS soft-bounded STDP update of W shard ----
        if (t + 1 < T_) {
            double ca0 = coaL[c2 * 2], ca1 = coaL[c2 * 2 + 1];
            double cb0 = cobL[c2 * 2], cb1 = cobL[c2 * 2 + 1];
            const double* prt = pre_tr   + (size_t)t * IN_;
            const double* prr = pre_rate + (size_t)t * IN_;
#pragma unroll 4
            for (int k = 0; k < 16; ++k) {
                int i = k * 128 + b;
                double p = prt[i], q = prr[i];
                double2* wp = (double2*)(smem + (SWADR(i) ^ cx));
                double2 w2 = *wp;
                double dw0 = ca0 * p - cb0 * q;
                double dw1 = ca1 * p - cb1 * q;
                double dwb0 = dw0 > 0.0 ? (dw0 * (MAXW_D - w2.x)) / 10.0
                                        : (dw0 * (w2.x - MINW_D)) / 10.0;
                double dwb1 = dw1 > 0.0 ? (dw1 * (MAXW_D - w2.y)) / 10.0
                                        : (dw1 * (w2.y - MINW_D)) / 10.0;
                double nw0 = w2.x + dwb0;
                nw0 = nw0 < MINW_D ? MINW_D : (nw0 > MAXW_D ? MAXW_D : nw0);
                double nw1 = w2.y + dwb1;
                nw1 = nw1 < MINW_D ? MINW_D : (nw1 > MAXW_D ? MAXW_D : nw1);
                *wp = make_double2(nw0, nw1);
            }
        }
        __syncthreads();
    }
}

extern "C" void kernel_launch(void* const* d_in, const int* in_sizes, int n_in,
                              void* d_out, int out_size, void* d_ws, size_t ws_size,
                              hipStream_t stream) {
    const float* x   = (const float*)d_in[0];
    const float* W   = (const float*)d_in[1];
    const float* thr = (const float*)d_in[2];
    const float* Ap  = (const float*)d_in[3];
    const float* Am  = (const float*)d_in[4];
    float* out = (float*)d_out;
    char* ws = (char*)d_ws;

    // workspace: pre_rate 1MB | pre_tr 1MB | idx 16.8MB | cnt 32KB  (~19 MB)
    double* pre_rate = (double*)(ws);
    double* pre_tr   = (double*)(ws + 1048576);
    unsigned* idx    = (unsigned*)(ws + 2097152);
    int* cnt         = (int*)(ws + 2097152 + 16777216);

    double decay = std::exp(-1.0 / 20.0);

    (void)hipFuncSetAttribute((const void*)k_main,
                              hipFuncAttributeMaxDynamicSharedMemorySize, SMEM_BYTES);

    k_rate<<<dim3(T_, IN_ / 256), 256, 0, stream>>>(x, pre_rate);
    k_scan<<<IN_ / 256, 256, 0, stream>>>(pre_rate, pre_tr, decay);
    k_build_idx<<<(B_ * T_) / 4, 256, 0, stream>>>(x, idx, cnt);
    k_main<<<256, 512, SMEM_BYTES, stream>>>(W, thr, Ap, Am, idx, cnt,
                                             pre_rate, pre_tr, out, decay);
}

// Round 4
// 835.300 us; speedup vs baseline: 3.7514x; 1.0526x over previous
//
#include <hip/hip_runtime.h>
#include <cmath>

#define B_   128
#define T_   64
#define IN_  2048
#define OUT_ 2048
#define IDXSTRIDE 512   // per (b,t): [0,256) even-i offsets, [256,512) odd-i offsets
#define HALFSTRIDE 256

// fp64 constants == Python float64 literals
#define BETA_D   0.9
#define ACTDEC_D 0.999
#define ETA_TH_D 0.001
#define TARGET_D 0.05
#define MINW_D   (-5.0)
#define MAXW_D   (5.0)
#define MINTH_D  0.5
#define MAXTH_D  2.0

// LDS: W 2048 rows x 8 cols fp64, row-major 64B rows.
//   byte(i, col o) = (i<<6) | ((o>>1)<<4) | ((o&1)<<3)
// part[2][8] f32 spike-count double buffer at 131072.
#define PART_OFF   131072
#define SMEM_BYTES 131136

// ---- precompute: pre_rate[t][i] = mean_b x[b,t,i]  (exact: integer counts) ----
__global__ __launch_bounds__(256) void k_rate(const float* __restrict__ x,
                                              double* __restrict__ pre_rate) {
    int t = blockIdx.x;
    int i = blockIdx.y * 256 + threadIdx.x;
    const float* xp = x + (size_t)t * IN_ + i;
    float s = 0.f;
    for (int b = 0; b < B_; ++b) s += xp[(size_t)b * T_ * IN_];
    pre_rate[(size_t)t * IN_ + i] = (double)s * (1.0 / 128.0);
}

// ---- precompute: pre_tr[t][i] = decay*pre_tr[t-1][i] + pre_rate[t][i] ----
__global__ __launch_bounds__(256) void k_scan(const double* __restrict__ pre_rate,
                                              double* __restrict__ pre_tr, double decay) {
    int i = blockIdx.x * 256 + threadIdx.x;
    double tr = 0.0;
    for (int t = 0; t < T_; ++t) {
        tr = decay * tr + pre_rate[(size_t)t * IN_ + i];
        pre_tr[(size_t)t * IN_ + i] = tr;
    }
}

// ---- ballot-compact x into PARITY-SPLIT lists of byte offsets (i<<6) per (b,t) ----
__global__ __launch_bounds__(256) void k_build_idx(const float* __restrict__ x,
        unsigned* __restrict__ idx, int* __restrict__ cnt) {
    int row  = blockIdx.x * 4 + (threadIdx.x >> 6);   // b*T + t
    int lane = threadIdx.x & 63;
    const float* xr = x + (size_t)row * IN_;
    unsigned* ip = idx + (size_t)row * IDXSTRIDE;
    const unsigned long long EVEN = 0x5555555555555555ull;
    unsigned long long below = (1ull << lane) - 1ull;
    int ce = 0, co = 0;
    for (int ch = 0; ch < IN_ / 64; ++ch) {
        int i = ch * 64 + lane;
        float vv = xr[i];
        unsigned long long m = __ballot(vv != 0.0f);
        unsigned long long me = m & EVEN, mo = m & ~EVEN;
        if (vv != 0.0f) {
            if ((lane & 1) == 0) {
                int pos = ce + __popcll(me & below);
                if (pos < HALFSTRIDE) ip[pos] = (unsigned)i << 6;
            } else {
                int pos = co + __popcll(mo & below);
                if (pos < HALFSTRIDE) ip[HALFSTRIDE + pos] = (unsigned)i << 6;
            }
        }
        ce += __popcll(me);
        co += __popcll(mo);
    }
    if (lane == 0) {
        if (ce > HALFSTRIDE) ce = HALFSTRIDE;
        if (co > HALFSTRIDE) co = HALFSTRIDE;
        cnt[row] = ce | (co << 16);
    }
}

// gather one col-pair given byte offset r (= i<<6)
#define GAT(r, A0, A1) do { \
    const double2 w_ = *(const double2*)(smem + ((r) ^ cx)); \
    A0 += w_.x; A1 += w_.y; } while (0)

// ---- persistent kernel: 256 blocks x 1024 threads; block s owns cols [s*8, s*8+8) ----
// tid = b*8 + c2*2 + h : b 0..127, c2 0..3 (col-pair), h 0..1 (even/odd sublist)
__global__ __launch_bounds__(1024, 4) void k_main(
        const float* __restrict__ W, const float* __restrict__ thr,
        const float* __restrict__ Ap, const float* __restrict__ Am,
        const unsigned* __restrict__ idx, const int* __restrict__ cnt,
        const double* __restrict__ pre_rate, const double* __restrict__ pre_tr,
        float* __restrict__ out, double decay) {
    extern __shared__ char smem[];
    float* part = (float*)(smem + PART_OFF);   // [2][8]

    const int tid  = threadIdx.x;
    const int s    = blockIdx.x;
    const int lane = tid & 63;
    const int h    = tid & 1;
    const int c2   = (tid >> 1) & 3;
    const int b    = tid >> 3;
    const unsigned cx = (unsigned)c2 << 4;

    // ---- prologue: load W shard (rows s*8..s*8+8 of W = our 8 cols) into LDS fp64 ----
#pragma unroll
    for (int o = 0; o < 8; ++o) {
        const float* wr = W + (size_t)(s * 8 + o) * IN_;
        for (int i = tid; i < IN_; i += 1024) {
            *(double*)(smem + (((unsigned)i << 6) | ((unsigned)(o >> 1) << 4)
                               | ((unsigned)(o & 1) << 3))) = (double)wr[i];
        }
    }
    if (tid < 16) part[tid] = 0.0f;

    // per-thread persistent state for this thread's 2 columns (replicated on both h)
    double th0 = (double)thr[s * 8 + c2 * 2];
    double th1 = (double)thr[s * 8 + c2 * 2 + 1];
    double ptr0 = 0.0, ptr1 = 0.0;
    double pact0 = TARGET_D, pact1 = TARGET_D;
    double vr0 = 0.0, vr1 = 0.0;                 // membrane (h==0 lanes only)
    const double apv = fabs((double)Ap[0]);
    const double amv = fabs((double)Am[0]);
    __syncthreads();

    for (int t = 0; t < T_; ++t) {
        const int pb = t & 1;
        // ---- P1: sparse fp64 gather (parity-split) + LIF + spike counts ----
        int row = b * T_ + t;
        int cc = cnt[row];
        int n = h ? (cc >> 16) : (cc & 0xffff);
        const unsigned* ip = idx + (size_t)row * IDXSTRIDE + h * HALFSTRIDE;
        double a0 = 0.0, a1 = 0.0, e0 = 0.0, e1 = 0.0;
        int n8 = n & ~7;
        int j = 0;
        if (n8 > 0) {
            uint4 q0 = *(const uint4*)(ip);
            uint4 q1 = *(const uint4*)(ip + 4);
            for (;;) {
                uint4 qa = q0, qb = q1;
                int jn = j + 8;
                if (jn < n8) {                        // prefetch next group
                    q0 = *(const uint4*)(ip + jn);
                    q1 = *(const uint4*)(ip + jn + 4);
                }
                GAT(qa.x, a0, a1); GAT(qa.y, e0, e1);
                GAT(qa.z, a0, a1); GAT(qa.w, e0, e1);
                GAT(qb.x, a0, a1); GAT(qb.y, e0, e1);
                GAT(qb.z, a0, a1); GAT(qb.w, e0, e1);
                j = jn;
                if (j >= n8) break;
            }
        }
        for (; j < n; ++j) { unsigned r = ip[j]; GAT(r, a0, a1); }
        a0 += e0; a1 += e1;
        // combine even/odd halves across the h-pair
        a0 += __shfl_xor(a0, 1);
        a1 += __shfl_xor(a1, 1);

        float s0 = 0.f, s1 = 0.f;
        if (h == 0) {
            double v0 = BETA_D * vr0 + a0;
            double v1 = BETA_D * vr1 + a1;
            s0 = (v0 >= th0) ? 1.0f : 0.0f;
            s1 = (v1 >= th1) ? 1.0f : 0.0f;
            *(float2*)(out + (size_t)row * OUT_ + s * 8 + c2 * 2) = make_float2(s0, s1);
            vr0 = (s0 != 0.0f) ? 0.0 : v0;
            vr1 = (s1 != 0.0f) ? 0.0 : v1;
        }

        if (t + 1 < T_) {
            // spike-count tree over the 8 b's in this wave (lane bits 3..5)
            float r0 = s0, r1 = s1;
            r0 += __shfl_xor(r0, 8);  r1 += __shfl_xor(r1, 8);
            r0 += __shfl_xor(r0, 16); r1 += __shfl_xor(r1, 16);
            r0 += __shfl_xor(r0, 32); r1 += __shfl_xor(r1, 32);
            if (lane < 8 && (lane & 1) == 0) {       // 4 lanes: one per c2
                atomicAdd(&part[pb * 8 + c2 * 2], r0);
                atomicAdd(&part[pb * 8 + c2 * 2 + 1], r1);
            }
            if (tid < 8) part[(pb ^ 1) * 8 + tid] = 0.0f;   // prep buffer for t+1
            __syncthreads();

            // ---- P2 (redundant per-thread): scalar chain for this thread's 2 cols ----
            float cf0 = part[pb * 8 + c2 * 2];
            float cf1 = part[pb * 8 + c2 * 2 + 1];
            double prate0 = (double)cf0 * (1.0 / 128.0);
            double prate1 = (double)cf1 * (1.0 / 128.0);
            ptr0 = decay * ptr0 + prate0;
            ptr1 = decay * ptr1 + prate1;
            pact0 = ACTDEC_D * pact0 + (1.0 - ACTDEC_D) * prate0;
            pact1 = ACTDEC_D * pact1 + (1.0 - ACTDEC_D) * prate1;
            double r_ = pact0 / TARGET_D;
            r_ = r_ < 0.5 ? 0.5 : (r_ > 2.0 ? 2.0 : r_);
            double meta0 = 1.0 / r_;
            r_ = pact1 / TARGET_D;
            r_ = r_ < 0.5 ? 0.5 : (r_ > 2.0 ? 2.0 : r_);
            double meta1 = 1.0 / r_;
            double ca0 = apv * prate0 * meta0;
            double ca1 = apv * prate1 * meta1;
            double cb0 = amv * ptr0 * meta0;
            double cb1 = amv * ptr1 * meta1;
            double thv = th0 * (1.0 + ETA_TH_D * (prate0 - TARGET_D));
            th0 = thv < MINTH_D ? MINTH_D : (thv > MAXTH_D ? MAXTH_D : thv);
            thv = th1 * (1.0 + ETA_TH_D * (prate1 - TARGET_D));
            th1 = thv < MINTH_D ? MINTH_D : (thv > MAXTH_D ? MAXTH_D : thv);

            // ---- P3: in-LDS soft-bounded STDP update of W shard ----
            const double* prt = pre_tr   + (size_t)t * IN_;
            const double* prr = pre_rate + (size_t)t * IN_;
            const int b2 = (b << 1) | h;             // 0..255
#pragma unroll
            for (int k = 0; k < 8; ++k) {
                int i = k * 256 + b2;
                double p = prt[i], q = prr[i];
                double2* wp = (double2*)(smem + (((unsigned)i << 6) | cx));
                double2 w2 = *wp;
                double dw0 = ca0 * p - cb0 * q;
                double dw1 = ca1 * p - cb1 * q;
                double dwb0 = dw0 > 0.0 ? (dw0 * (MAXW_D - w2.x)) / 10.0
                                        : (dw0 * (w2.x - MINW_D)) / 10.0;
                double dwb1 = dw1 > 0.0 ? (dw1 * (MAXW_D - w2.y)) / 10.0
                                        : (dw1 * (w2.y - MINW_D)) / 10.0;
                double nw0 = w2.x + dwb0;
                nw0 = nw0 < MINW_D ? MINW_D : (nw0 > MAXW_D ? MAXW_D : nw0);
                double nw1 = w2.y + dwb1;
                nw1 = nw1 < MINW_D ? MINW_D : (nw1 > MAXW_D ? MAXW_D : nw1);
                *wp = make_double2(nw0, nw1);
            }
            __syncthreads();
        }
    }
}

extern "C" void kernel_launch(void* const* d_in, const int* in_sizes, int n_in,
                              void* d_out, int out_size, void* d_ws, size_t ws_size,
                              hipStream_t stream) {
    const float* x   = (const float*)d_in[0];
    const float* W   = (const float*)d_in[1];
    const float* thr = (const float*)d_in[2];
    const float* Ap  = (const float*)d_in[3];
    const float* Am  = (const float*)d_in[4];
    float* out = (float*)d_out;
    char* ws = (char*)d_ws;

    // workspace: pre_rate 1MB | pre_tr 1MB | idx 16.8MB | cnt 32KB
    double* pre_rate = (double*)(ws);
    double* pre_tr   = (double*)(ws + 1048576);
    unsigned* idx    = (unsigned*)(ws + 2097152);
    int* cnt         = (int*)(ws + 2097152 + 16777216);

    double decay = std::exp(-1.0 / 20.0);

    (void)hipFuncSetAttribute((const void*)k_main,
                              hipFuncAttributeMaxDynamicSharedMemorySize, SMEM_BYTES);

    k_rate<<<dim3(T_, IN_ / 256), 256, 0, stream>>>(x, pre_rate);
    k_scan<<<IN_ / 256, 256, 0, stream>>>(pre_rate, pre_tr, decay);
    k_build_idx<<<(B_ * T_) / 4, 256, 0, stream>>>(x, idx, cnt);
    k_main<<<256, 1024, SMEM_BYTES, stream>>>(W, thr, Ap, Am, idx, cnt,
                                              pre_rate, pre_tr, out, decay);
}

// Round 5
// 835.008 us; speedup vs baseline: 3.7527x; 1.0003x over previous
//
#include <hip/hip_runtime.h>
#include <cmath>

#define B_   128
#define T_   64
#define IN_  2048
#define OUT_ 2048
#define IDXSTRIDE 512   // per (b,t): [0,256) half-0, [256,512) half-1 (balanced interleave)
#define HALFSTRIDE 256
#define ZOFF 131072u    // byte offset of the 64B zero row (row index 2048)

// fp64 constants == Python float64 literals
#define BETA_D   0.9
#define ACTDEC_D 0.999
#define ETA_TH_D 0.001
#define TARGET_D 0.05
#define MINW_D   (-5.0)
#define MAXW_D   (5.0)
#define MINTH_D  0.5
#define MAXTH_D  2.0

// LDS: W 2048 rows x 8 cols fp64, row-major 64B rows:
//   byte(i, col o) = (i<<6) | ((o>>1)<<4) | ((o&1)<<3)
// row 2048 (at ZOFF) is all zeros -- target of list padding entries.
// part[2][8] f32 spike-count double buffer after that.
#define PART_OFF   131136
#define SMEM_BYTES 131200

// ---- precompute: pre_rate[t][i] = mean_b x[b,t,i]  (exact: integer counts) ----
__global__ __launch_bounds__(256) void k_rate(const float* __restrict__ x,
                                              double* __restrict__ pre_rate) {
    int t = blockIdx.x;
    int i = blockIdx.y * 256 + threadIdx.x;
    const float* xp = x + (size_t)t * IN_ + i;
    float s = 0.f;
    for (int b = 0; b < B_; ++b) s += xp[(size_t)b * T_ * IN_];
    pre_rate[(size_t)t * IN_ + i] = (double)s * (1.0 / 128.0);
}

// ---- precompute: pre_tr[t][i] = decay*pre_tr[t-1][i] + pre_rate[t][i] ----
__global__ __launch_bounds__(256) void k_scan(const double* __restrict__ pre_rate,
                                              double* __restrict__ pre_tr, double decay) {
    int i = blockIdx.x * 256 + threadIdx.x;
    double tr = 0.0;
    for (int t = 0; t < T_; ++t) {
        tr = decay * tr + pre_rate[(size_t)t * IN_ + i];
        pre_tr[(size_t)t * IN_ + i] = tr;
    }
}

// ---- ballot-compact x into BALANCED interleaved half-lists, padded to 8 with ZOFF ----
__global__ __launch_bounds__(256) void k_build_idx(const float* __restrict__ x,
        unsigned* __restrict__ idx, int* __restrict__ cnt) {
    int row  = blockIdx.x * 4 + (threadIdx.x >> 6);   // b*T + t
    int lane = threadIdx.x & 63;
    const float* xr = x + (size_t)row * IN_;
    unsigned* ip = idx + (size_t)row * IDXSTRIDE;
    unsigned long long below = (1ull << lane) - 1ull;
    int c = 0;
    for (int ch = 0; ch < IN_ / 64; ++ch) {
        int i = ch * 64 + lane;
        float vv = xr[i];
        unsigned long long m = __ballot(vv != 0.0f);
        if (vv != 0.0f) {
            int pos  = c + __popcll(m & below);
            int half = pos & 1, slot = pos >> 1;
            if (slot < HALFSTRIDE) ip[half * HALFSTRIDE + slot] = (unsigned)i << 6;
        }
        c += __popcll(m);
    }
    int ce = (c + 1) >> 1; if (ce > HALFSTRIDE) ce = HALFSTRIDE;
    int co = c >> 1;       if (co > HALFSTRIDE) co = HALFSTRIDE;
    int np = ((ce > co ? ce : co) + 7) & ~7;          // common padded length, mult of 8
    for (int p = ce + lane; p < np; p += 64) ip[p] = ZOFF;
    for (int p = co + lane; p < np; p += 64) ip[HALFSTRIDE + p] = ZOFF;
    if (lane == 0) cnt[row] = np;
}

// gather one col-pair given byte offset r (= i<<6, bits 0..5 clear)
#define GAT(r, A0, A1) do { \
    const double2 w_ = *(const double2*)(smem + ((r) ^ cx)); \
    A0 += w_.x; A1 += w_.y; } while (0)

// ---- persistent kernel: 256 blocks x 1024 threads; block s owns cols [s*8, s*8+8) ----
// tid = b*8 + c2*2 + h : b 0..127, c2 0..3 (col-pair), h 0..1 (half-list)
__global__ __launch_bounds__(1024, 4) void k_main(
        const float* __restrict__ W, const float* __restrict__ thr,
        const float* __restrict__ Ap, const float* __restrict__ Am,
        const unsigned* __restrict__ idx, const int* __restrict__ cnt,
        const double* __restrict__ pre_rate, const double* __restrict__ pre_tr,
        float* __restrict__ out, double decay) {
    extern __shared__ char smem[];
    float* part = (float*)(smem + PART_OFF);   // [2][8]

    const int tid  = threadIdx.x;
    const int s    = blockIdx.x;
    const int lane = tid & 63;
    const int h    = tid & 1;
    const int c2   = (tid >> 1) & 3;
    const int b    = tid >> 3;
    const unsigned cx = (unsigned)c2 << 4;

    // ---- prologue: load W shard (rows s*8..s*8+8 of W = our 8 cols) into LDS fp64 ----
#pragma unroll
    for (int o = 0; o < 8; ++o) {
        const float* wr = W + (size_t)(s * 8 + o) * IN_;
        for (int i = tid; i < IN_; i += 1024) {
            *(double*)(smem + (((unsigned)i << 6) | ((unsigned)(o >> 1) << 4)
                               | ((unsigned)(o & 1) << 3))) = (double)wr[i];
        }
    }
    if (tid < 8)  ((double*)(smem + ZOFF))[tid] = 0.0;   // zero row for padding entries
    if (tid < 16) part[tid] = 0.0f;

    // per-thread persistent state for this thread's 2 columns (replicated on both h)
    double th0 = (double)thr[s * 8 + c2 * 2];
    double th1 = (double)thr[s * 8 + c2 * 2 + 1];
    double ptr0 = 0.0, ptr1 = 0.0;
    double pact0 = TARGET_D, pact1 = TARGET_D;
    double vr0 = 0.0, vr1 = 0.0;                 // membrane (h==0 lanes authoritative)
    const double apv = fabs((double)Ap[0]);
    const double amv = fabs((double)Am[0]);
    __syncthreads();

    // preload step-0 list head (count + first 8 entries)
    const unsigned* ip0 = idx + (size_t)(b * T_) * IDXSTRIDE + h * HALFSTRIDE;
    int   n  = cnt[b * T_];
    uint4 q0 = *(const uint4*)(ip0);
    uint4 q1 = *(const uint4*)(ip0 + 4);

    for (int t = 0; t < T_; ++t) {
        const int pb = t & 1;
        const int row = b * T_ + t;
        const unsigned* ip = idx + (size_t)row * IDXSTRIDE + h * HALFSTRIDE;

        // ---- P1: sparse fp64 gather (balanced halves, 8-padded: no tail) ----
        double a0 = 0.0, a1 = 0.0, e0 = 0.0, e1 = 0.0;
        if (n > 0) {
            int j = 0;
            for (;;) {
                uint4 qa = q0, qb = q1;
                int jn = j + 8;
                if (jn < n) {                         // prefetch next group
                    q0 = *(const uint4*)(ip + jn);
                    q1 = *(const uint4*)(ip + jn + 4);
                }
                GAT(qa.x, a0, a1); GAT(qa.y, e0, e1);
                GAT(qa.z, a0, a1); GAT(qa.w, e0, e1);
                GAT(qb.x, a0, a1); GAT(qb.y, e0, e1);
                GAT(qb.z, a0, a1); GAT(qb.w, e0, e1);
                j = jn;
                if (j >= n) break;
            }
        }
        a0 += e0; a1 += e1;
        // combine the two halves across the h-pair (commutative: both lanes identical)
        a0 += __shfl_xor(a0, 1);
        a1 += __shfl_xor(a1, 1);

        // prefetch next step's list head NOW (read-only; hides under P2/P3 + barriers)
        {
            int rown = row + ((t + 1 < T_) ? 1 : 0);
            const unsigned* ipn = idx + (size_t)rown * IDXSTRIDE + h * HALFSTRIDE;
            n  = cnt[rown];
            q0 = *(const uint4*)(ipn);
            q1 = *(const uint4*)(ipn + 4);
        }

        float s0 = 0.f, s1 = 0.f;
        if (h == 0) {
            double v0 = BETA_D * vr0 + a0;
            double v1 = BETA_D * vr1 + a1;
            s0 = (v0 >= th0) ? 1.0f : 0.0f;
            s1 = (v1 >= th1) ? 1.0f : 0.0f;
            *(float2*)(out + (size_t)row * OUT_ + s * 8 + c2 * 2) = make_float2(s0, s1);
            vr0 = (s0 != 0.0f) ? 0.0 : v0;
            vr1 = (s1 != 0.0f) ? 0.0 : v1;
        }

        if (t + 1 < T_) {
            // spike-count tree over the 8 b's in this wave (lane bits 3..5)
            float r0 = s0, r1 = s1;
            r0 += __shfl_xor(r0, 8);  r1 += __shfl_xor(r1, 8);
            r0 += __shfl_xor(r0, 16); r1 += __shfl_xor(r1, 16);
            r0 += __shfl_xor(r0, 32); r1 += __shfl_xor(r1, 32);
            if (lane < 8 && (lane & 1) == 0) {       // 4 lanes: one per c2
                atomicAdd(&part[pb * 8 + c2 * 2], r0);
                atomicAdd(&part[pb * 8 + c2 * 2 + 1], r1);
            }
            if (tid < 8) part[(pb ^ 1) * 8 + tid] = 0.0f;   // prep buffer for t+1
            __syncthreads();

            // ---- P2 (redundant per-thread): scalar chain for this thread's 2 cols ----
            float cf0 = part[pb * 8 + c2 * 2];
            float cf1 = part[pb * 8 + c2 * 2 + 1];
            double prate0 = (double)cf0 * (1.0 / 128.0);
            double prate1 = (double)cf1 * (1.0 / 128.0);
            ptr0 = decay * ptr0 + prate0;
            ptr1 = decay * ptr1 + prate1;
            pact0 = ACTDEC_D * pact0 + (1.0 - ACTDEC_D) * prate0;
            pact1 = ACTDEC_D * pact1 + (1.0 - ACTDEC_D) * prate1;
            double r_ = pact0 / TARGET_D;
            r_ = r_ < 0.5 ? 0.5 : (r_ > 2.0 ? 2.0 : r_);
            double meta0 = 1.0 / r_;
            r_ = pact1 / TARGET_D;
            r_ = r_ < 0.5 ? 0.5 : (r_ > 2.0 ? 2.0 : r_);
            double meta1 = 1.0 / r_;
            double ca0 = apv * prate0 * meta0;
            double ca1 = apv * prate1 * meta1;
            double cb0 = amv * ptr0 * meta0;
            double cb1 = amv * ptr1 * meta1;
            double thv = th0 * (1.0 + ETA_TH_D * (prate0 - TARGET_D));
            th0 = thv < MINTH_D ? MINTH_D : (thv > MAXTH_D ? MAXTH_D : thv);
            thv = th1 * (1.0 + ETA_TH_D * (prate1 - TARGET_D));
            th1 = thv < MINTH_D ? MINTH_D : (thv > MAXTH_D ? MAXTH_D : thv);

            // ---- P3: in-LDS soft-bounded STDP update of W shard ----
            const double* prt = pre_tr   + (size_t)t * IN_;
            const double* prr = pre_rate + (size_t)t * IN_;
            const int b2 = (b << 1) | h;             // 0..255
#pragma unroll
            for (int k = 0; k < 8; ++k) {
                int i = k * 256 + b2;
                double p = prt[i], q = prr[i];
                double2* wp = (double2*)(smem + (((unsigned)i << 6) | cx));
                double2 w2 = *wp;
                double dw0 = ca0 * p - cb0 * q;
                double dw1 = ca1 * p - cb1 * q;
                double dwb0 = dw0 > 0.0 ? (dw0 * (MAXW_D - w2.x)) / 10.0
                                        : (dw0 * (w2.x - MINW_D)) / 10.0;
                double dwb1 = dw1 > 0.0 ? (dw1 * (MAXW_D - w2.y)) / 10.0
                                        : (dw1 * (w2.y - MINW_D)) / 10.0;
                double nw0 = w2.x + dwb0;
                nw0 = nw0 < MINW_D ? MINW_D : (nw0 > MAXW_D ? MAXW_D : nw0);
                double nw1 = w2.y + dwb1;
                nw1 = nw1 < MINW_D ? MINW_D : (nw1 > MAXW_D ? MAXW_D : nw1);
                *wp = make_double2(nw0, nw1);
            }
            __syncthreads();
        }
    }
}

extern "C" void kernel_launch(void* const* d_in, const int* in_sizes, int n_in,
                              void* d_out, int out_size, void* d_ws, size_t ws_size,
                              hipStream_t stream) {
    const float* x   = (const float*)d_in[0];
    const float* W   = (const float*)d_in[1];
    const float* thr = (const float*)d_in[2];
    const float* Ap  = (const float*)d_in[3];
    const float* Am  = (const float*)d_in[4];
    float* out = (float*)d_out;
    char* ws = (char*)d_ws;

    // workspace: pre_rate 1MB | pre_tr 1MB | idx 16.8MB | cnt 32KB
    double* pre_rate = (double*)(ws);
    double* pre_tr   = (double*)(ws + 1048576);
    unsigned* idx    = (unsigned*)(ws + 2097152);
    int* cnt         = (int*)(ws + 2097152 + 16777216);

    double decay = std::exp(-1.0 / 20.0);

    (void)hipFuncSetAttribute((const void*)k_main,
                              hipFuncAttributeMaxDynamicSharedMemorySize, SMEM_BYTES);

    k_rate<<<dim3(T_, IN_ / 256), 256, 0, stream>>>(x, pre_rate);
    k_scan<<<IN_ / 256, 256, 0, stream>>>(pre_rate, pre_tr, decay);
    k_build_idx<<<(B_ * T_) / 4, 256, 0, stream>>>(x, idx, cnt);
    k_main<<<256, 1024, SMEM_BYTES, stream>>>(W, thr, Ap, Am, idx, cnt,
                                              pre_rate, pre_tr, out, decay);
}